// Round 5
// baseline (275.048 us; speedup 1.0000x reference)
//
#include <hip/hip_runtime.h>
#include <hip/hip_bf16.h>
#include <cstdint>
#include <cstddef>

// Problem constants (fixed by the reference)
#define NCAT   8
#define DIN    64
#define HID    1024
#define NBATCH 256
#define HSEQ   64
#define NTOK   (NBATCH * HSEQ)   // 16384
#define MAXTILES 132             // 2-batch tiles (L1): sum ceil(nb_c/2) <= 132
#define NWG (4 * MAXTILES)       // 528 = 8 * 66
#define MAXT4 72                 // 4-batch tiles: sum ceil(nb_c/4) <= 70, pad to 72
#define NWG2 (4 * MAXT4)         // 288 = 8 * 36 (clean XCD swizzle)

typedef __bf16 bf16x8 __attribute__((ext_vector_type(8)));
typedef __bf16 bf16x4 __attribute__((ext_vector_type(4)));
typedef float  f32x4  __attribute__((ext_vector_type(4)));

__device__ __forceinline__ void async16(const void* g, void* l) {
    __builtin_amdgcn_global_load_lds(
        (const __attribute__((address_space(1))) unsigned int*)g,
        (__attribute__((address_space(3))) unsigned int*)l,
        16, 0, 0);
}

// ---------------- setup: counting-sort batches by category, build tile tables ----------------
// meta (ints): order[256]@0, tileB0[..]@256, tileB1[..]@416, tileCat[..]@576,
// ntiles@736, t4b[4*MAXT4]@800, t4cat[MAXT4]@1100, nt4@1180
__global__ void setup_kernel(const int* __restrict__ cat, int* __restrict__ meta) {
    __shared__ int scat[NBATCH];
    __shared__ int cnt[NCAT], pfx[NCAT + 1];
    const int tid = threadIdx.x;
    const int c = cat[tid];
    scat[tid] = c;
    if (tid < NCAT) cnt[tid] = 0;
    __syncthreads();
    atomicAdd(&cnt[c], 1);
    __syncthreads();
    if (tid == 0) {
        pfx[0] = 0;
        for (int i = 0; i < NCAT; ++i) pfx[i + 1] = pfx[i] + cnt[i];
    }
    __syncthreads();
    int r = 0;
    for (int b = 0; b < tid; ++b) r += (scat[b] == c);
    meta[pfx[c] + r] = tid;                 // order[]
    __threadfence();
    __syncthreads();
    if (tid == 0) {
        int nt = 0, nt4 = 0;
        for (int cc = 0; cc < NCAT; ++cc) {
            const int base = pfx[cc], n = cnt[cc];
            for (int j = 0; j < n; j += 2) {
                meta[256 + nt] = meta[base + j];
                meta[416 + nt] = (j + 1 < n) ? meta[base + j + 1] : -1;
                meta[576 + nt] = cc;
                ++nt;
            }
            for (int j = 0; j < n; j += 4) {
                for (int q = 0; q < 4; ++q)
                    meta[800 + nt4 * 4 + q] = (j + q < n) ? meta[base + j + q] : -1;
                meta[1100 + nt4] = cc;
                ++nt4;
            }
        }
        meta[736] = nt;
        meta[1180] = nt4;
    }
}

// ---------------- prep kernels ----------------

__global__ void pe_kernel(float* __restrict__ pe) {
    const int t = blockIdx.x;        // 0..63
    const int i = threadIdx.x;       // 0..511
    const float div = expf((float)(2 * i) * (-9.210340371976184f / 1024.f));
    const float a = (float)t * div;
    pe[t * HID + 2 * i]     = sinf(a);
    pe[t * HID + 2 * i + 1] = cosf(a);
}

__global__ void cvt_x_kernel(const float* __restrict__ x, __bf16* __restrict__ xb) {
    const size_t i = (size_t)blockIdx.x * blockDim.x + threadIdx.x;
    const float4 v = ((const float4*)x)[i];
    bf16x4 o = { (__bf16)v.x, (__bf16)v.y, (__bf16)v.z, (__bf16)v.w };
    *(bf16x4*)(xb + 4 * i) = o;
}

// W [C][K][N] f32 -> Wt [C][N][K] bf16 (64x64 LDS-tiled transpose)
template <int WHICH>
__global__ __launch_bounds__(256)
void transpose_kernel(const float* __restrict__ W, __bf16* __restrict__ Wt,
                      const int K, const int N) {
    __shared__ float tile[64][65];
    const int c = blockIdx.z;
    const float* Wc = W + (size_t)c * K * N;
    __bf16* Wtc = Wt + (size_t)c * N * K;
    const int k0 = blockIdx.y * 64, n0 = blockIdx.x * 64;
    const int t = threadIdx.x;
    const int cl = (t & 15) * 4, rw = t >> 4;
#pragma unroll
    for (int p = 0; p < 4; ++p) {
        const int r = rw + p * 16;
        const float4 v = *(const float4*)(Wc + (size_t)(k0 + r) * N + (n0 + cl));
        tile[r][cl]     = v.x;
        tile[r][cl + 1] = v.y;
        tile[r][cl + 2] = v.z;
        tile[r][cl + 3] = v.w;
    }
    __syncthreads();
    const int n = t >> 2, ks = (t & 3) * 16;
    bf16x8 o0, o1;
#pragma unroll
    for (int i = 0; i < 8; ++i) o0[i] = (__bf16)tile[ks + i][n];
#pragma unroll
    for (int i = 0; i < 8; ++i) o1[i] = (__bf16)tile[ks + 8 + i][n];
    __bf16* dst = Wtc + (size_t)(n0 + n) * K + (k0 + ks);
    *(bf16x8*)dst = o0;
    *(bf16x8*)(dst + 8) = o1;
}

// ---------------- L1: 128x256 2-batch GEMM (round-4 body, K=64) ----------------
__global__ __launch_bounds__(512, 2)
void gemm_l1(const __bf16* __restrict__ A, const __bf16* __restrict__ Bt,
             const float* __restrict__ bias, const float* __restrict__ pe,
             const int* __restrict__ meta, __bf16* __restrict__ hout) {
    constexpr int K = DIN;
    __shared__ __bf16 Ab[128 * 64];
    __shared__ __bf16 Bb[256 * 64];
    const int tid = threadIdx.x;
    const int lane = tid & 63;
    const int wv = tid >> 6;
    const int wm = wv >> 2, wn = wv & 3;
    const int orig = blockIdx.x;
    const int wgid = (orig & 7) * 66 + (orig >> 3);
    const int mt = wgid >> 2;
    const int n0 = (wgid & 3) * 256;
    if (mt >= meta[736]) return;
    const int b0  = meta[256 + mt];
    const int b1  = meta[416 + mt];
    const int cid = meta[576 + mt];
    const int bb  = (b1 < 0) ? b0 : b1;

    const char* Ag0 = (const char*)(A + (size_t)b0 * HSEQ * K);
    const char* Ag1 = (const char*)(A + (size_t)bb * HSEQ * K);
    const char* Bg  = (const char*)(Bt + ((size_t)cid * HID + n0) * K);

    const int srow = tid >> 3;
    const int scol_sw = (((tid & 7) ^ (srow & 7)) * 16);

    async16(Ag0 + (size_t)srow * (K * 2) + scol_sw, (char*)Ab + tid * 16);
    async16(Ag1 + (size_t)srow * (K * 2) + scol_sw, (char*)Ab + 8192 + tid * 16);
#pragma unroll
    for (int j = 0; j < 4; ++j)
        async16(Bg + (size_t)(j * 64 + srow) * (K * 2) + scol_sw,
                (char*)Bb + j * 8192 + tid * 16);

    f32x4 acc[4][4] = {};
    const int lr = lane & 15, lh = lane >> 4;
    const int rsw = lr & 7;
    asm volatile("s_waitcnt vmcnt(0)" ::: "memory");
    __builtin_amdgcn_s_barrier();
#pragma unroll
    for (int kk = 0; kk < 2; ++kk) {
        bf16x8 af[4], bfr[4];
        const int soff = ((((kk << 2) | lh) ^ rsw) << 4);
#pragma unroll
        for (int mi = 0; mi < 4; ++mi)
            af[mi] = *(const bf16x8*)((const char*)Ab + (wm * 64 + mi * 16 + lr) * 128 + soff);
#pragma unroll
        for (int ni = 0; ni < 4; ++ni)
            bfr[ni] = *(const bf16x8*)((const char*)Bb + (wn * 64 + ni * 16 + lr) * 128 + soff);
#pragma unroll
        for (int mi = 0; mi < 4; ++mi)
#pragma unroll
            for (int ni = 0; ni < 4; ++ni)
                acc[mi][ni] = __builtin_amdgcn_mfma_f32_16x16x32_bf16(
                    af[mi], bfr[ni], acc[mi][ni], 0, 0, 0);
    }

    const bool doStore = (wm == 0) || (b1 >= 0);
    if (!doStore) return;
    const int batch = wm ? b1 : b0;
#pragma unroll
    for (int ni = 0; ni < 4; ++ni) {
        const int n = n0 + wn * 64 + ni * 16 + lr;
        const float bv = bias[cid * HID + n];
#pragma unroll
        for (int mi = 0; mi < 4; ++mi) {
#pragma unroll
            for (int r = 0; r < 4; ++r) {
                const int tok = mi * 16 + lh * 4 + r;
                const size_t gi = ((size_t)batch * HSEQ + tok) * HID + n;
                float v = fmaxf(acc[mi][ni][r] + bv, 0.f) + pe[tok * HID + n];
                hout[gi] = (__bf16)v;
            }
        }
    }
}

// ---------------- L2/L3: 256x256 4-batch GEMM, 8-phase (m201 template) ----------------
// K = 1024 = 16 K-tiles of BK=64. LDS = 2-deep K-tile ring (A 32K + B 32K each).
// Per K-tile: 4 phases (mhalf,kk) each {ds_read frags -> s_barrier -> lgkmcnt(0)
// -> setprio(1) 16 MFMA setprio(0) -> s_barrier}; stage K-tile k+1 in phases 0
// (A, 4 gloads) and 1 (B, 4 gloads); vmcnt(0) only at phase-3 end (exact count:
// only k+1's loads outstanding, issued 2-4 phases earlier). T2 slot-XOR swizzle
// on global source + ds_read (LDS dest linear). T1 XCD swizzle (288 = 8*36).
// EPI: 1 = +bias, relu -> bf16 ; 2 = +bias -> f32
template <int EPI>
__device__ __forceinline__ void gemm_body8(
        const __bf16* __restrict__ A, const __bf16* __restrict__ Bt,
        const float* __restrict__ bias, const int* __restrict__ meta,
        __bf16* __restrict__ hout, float* __restrict__ fout) {
    constexpr int K = HID;
    constexpr int NKT = K / 64;          // 16
    __shared__ __bf16 Ab[2][256 * 64];   // 2 x 32 KB
    __shared__ __bf16 Bb[2][256 * 64];   // 2 x 32 KB
    const int tid = threadIdx.x;         // 0..511
    const int lane = tid & 63;
    const int wv = tid >> 6;             // 0..7
    const int wm = wv >> 2, wn = wv & 3; // 2M x 4N
    const int orig = blockIdx.x;
    const int wgid = (orig & 7) * 36 + (orig >> 3);   // bijective XCD swizzle
    const int mt = wgid >> 2;
    const int n0 = (wgid & 3) * 256;
    if (mt >= meta[1180]) return;
    int bt[4];
#pragma unroll
    for (int q = 0; q < 4; ++q) bt[q] = meta[800 + mt * 4 + q];
    const int cid = meta[1100 + mt];

    const char* Agc[4];
#pragma unroll
    for (int q = 0; q < 4; ++q) {
        const int bq = (bt[q] < 0) ? bt[0] : bt[q];
        Agc[q] = (const char*)(A + (size_t)bq * HSEQ * K);
    }
    const char* Bgc = (const char*)(Bt + ((size_t)cid * HID + n0) * K);

    // staging: 512 thr x 16B = 8 KB = 64 rows of 128 B per gload
    const int srow = tid >> 3;           // 0..63
    const int scol_sw = (((tid & 7) ^ (srow & 7)) * 16);   // T2 pre-swizzled source

    auto stageA = [&](int buf, int kt) {
        const size_t kb = (size_t)kt * 128;
#pragma unroll
        for (int q = 0; q < 4; ++q)
            async16(Agc[q] + (size_t)srow * (2 * K) + kb + scol_sw,
                    (char*)&Ab[buf][0] + q * 8192 + tid * 16);
    };
    auto stageB = [&](int buf, int kt) {
        const size_t kb = (size_t)kt * 128;
#pragma unroll
        for (int j = 0; j < 4; ++j)
            async16(Bgc + (size_t)(j * 64 + srow) * (2 * K) + kb + scol_sw,
                    (char*)&Bb[buf][0] + j * 8192 + tid * 16);
    };

    f32x4 acc[8][4] = {};
    const int lr = lane & 15, lh = lane >> 4;
    const int rsw = lr & 7;

    // prologue: stage K-tile 0 into buf 0
    stageA(0, 0);
    stageB(0, 0);
    asm volatile("s_waitcnt vmcnt(0)" ::: "memory");
    __builtin_amdgcn_s_barrier();

    for (int k = 0; k < NKT; ++k) {
        const int c = k & 1;
        const char* Abase = (const char*)&Ab[c][0];
        const char* Bbase = (const char*)&Bb[c][0];
        const bool more = (k + 1 < NKT);
        bf16x8 bfr[4];
#pragma unroll
        for (int p = 0; p < 4; ++p) {
            const int h = p & 1, kk = p >> 1;
            const int soff = ((((kk << 2) | lh) ^ rsw) << 4);
            bf16x8 af[4];
            if ((p & 1) == 0) {          // kk start: load B frags (reused next phase)
#pragma unroll
                for (int ni = 0; ni < 4; ++ni)
                    bfr[ni] = *(const bf16x8*)(Bbase + (wn * 64 + ni * 16 + lr) * 128 + soff);
            }
#pragma unroll
            for (int mi = 0; mi < 4; ++mi)
                af[mi] = *(const bf16x8*)(Abase + (wm * 128 + h * 64 + mi * 16 + lr) * 128 + soff);
            if (more) {                  // front-loaded staging of K-tile k+1
                if (p == 0) stageA(1 - c, k + 1);
                else if (p == 1) stageB(1 - c, k + 1);
            }
            __builtin_amdgcn_sched_barrier(0);
            __builtin_amdgcn_s_barrier();
            asm volatile("s_waitcnt lgkmcnt(0)" ::: "memory");
            __builtin_amdgcn_sched_barrier(0);
            __builtin_amdgcn_s_setprio(1);
#pragma unroll
            for (int mi = 0; mi < 4; ++mi)
#pragma unroll
                for (int ni = 0; ni < 4; ++ni)
                    acc[h * 4 + mi][ni] = __builtin_amdgcn_mfma_f32_16x16x32_bf16(
                        af[mi], bfr[ni], acc[h * 4 + mi][ni], 0, 0, 0);
            __builtin_amdgcn_s_setprio(0);
            __builtin_amdgcn_sched_barrier(0);
            if (p == 3) asm volatile("s_waitcnt vmcnt(0)" ::: "memory");
            __builtin_amdgcn_s_barrier();
            __builtin_amdgcn_sched_barrier(0);
        }
    }

    // epilogue: C/D layout col = lane&15, row = (lane>>4)*4 + r
#pragma unroll
    for (int M = 0; M < 8; ++M) {
        const int q = 2 * wm + (M >> 2);
        const int bq = bt[q];
        if (bq < 0) continue;
        const int tokbase = ((M * 16) & 63) + lh * 4;
#pragma unroll
        for (int ni = 0; ni < 4; ++ni) {
            const int n = n0 + wn * 64 + ni * 16 + lr;
            const float bv = bias[cid * HID + n];
#pragma unroll
            for (int r = 0; r < 4; ++r) {
                const size_t gi = ((size_t)bq * HSEQ + tokbase + r) * HID + n;
                float v = acc[M][ni][r] + bv;
                if constexpr (EPI == 1) {
                    hout[gi] = (__bf16)fmaxf(v, 0.f);
                } else {
                    fout[gi] = v;
                }
            }
        }
    }
}

__global__ __launch_bounds__(512, 2)
void gemm_l2(const __bf16* __restrict__ A, const __bf16* __restrict__ Bt,
             const float* __restrict__ bias,
             const int* __restrict__ meta, __bf16* __restrict__ hout) {
    gemm_body8<1>(A, Bt, bias, meta, hout, nullptr);
}
__global__ __launch_bounds__(512, 2)
void gemm_l3(const __bf16* __restrict__ A, const __bf16* __restrict__ Bt,
             const float* __restrict__ bias,
             const int* __restrict__ meta, float* __restrict__ fout) {
    gemm_body8<2>(A, Bt, bias, meta, nullptr, fout);
}

// ---------------- launcher ----------------

extern "C" void kernel_launch(void* const* d_in, const int* in_sizes, int n_in,
                              void* d_out, int out_size, void* d_ws, size_t ws_size,
                              hipStream_t stream) {
    (void)in_sizes; (void)n_in; (void)out_size; (void)ws_size;
    const float* x   = (const float*)d_in[0];
    const int*   cat = (const int*)d_in[1];
    const float* W1  = (const float*)d_in[2];
    const float* b1  = (const float*)d_in[3];
    const float* W2  = (const float*)d_in[4];
    const float* b2  = (const float*)d_in[5];
    const float* W3  = (const float*)d_in[6];
    const float* b3  = (const float*)d_in[7];
    float* out = (float*)d_out;

    // Workspace layout (67.1 MB; xb/W1t/pe are dead after L1 and time-alias h2):
    char* ws = (char*)d_ws;
    int*    meta = (int*)ws;                             // [0, 8192)
    __bf16* xb   = (__bf16*)(ws + 8192);                 // 2 MB   (L1 only)
    __bf16* W1t  = (__bf16*)(ws + 8192 + 2097152);       // 1 MB   (L1 only)
    float*  pe   = (float*) (ws + 8192 + 3145728);       // 256 KB (L1 only)
    __bf16* h2   = (__bf16*)(ws + 8192);                 // 32 MB  (aliases the above)
    __bf16* W2t  = (__bf16*)(ws + 33562624);             // 16 MB
    __bf16* W3t  = (__bf16*)(ws + 50339840);             // 16 MB
    // h1 (bf16, 32 MB) lives in the first half of d_out (f32 64 MB);
    // fully consumed by L2 before L3 overwrites d_out.
    __bf16* h1 = (__bf16*)d_out;

    setup_kernel<<<dim3(1), dim3(NBATCH), 0, stream>>>(cat, meta);
    pe_kernel<<<dim3(HSEQ), dim3(512), 0, stream>>>(pe);
    cvt_x_kernel<<<dim3(NTOK * DIN / 4 / 256), dim3(256), 0, stream>>>(x, xb);
    transpose_kernel<1><<<dim3(16, 1, NCAT),  dim3(256), 0, stream>>>(W1, W1t, DIN, HID);
    transpose_kernel<2><<<dim3(16, 16, NCAT), dim3(256), 0, stream>>>(W2, W2t, HID, HID);
    transpose_kernel<3><<<dim3(16, 16, NCAT), dim3(256), 0, stream>>>(W3, W3t, HID, HID);

    gemm_l1<<<dim3(NWG), dim3(512), 0, stream>>>(xb, W1t, b1, pe, meta, h1);
    gemm_l2<<<dim3(NWG2), dim3(512), 0, stream>>>(h1, W2t, b2, meta, h2);
    gemm_l3<<<dim3(NWG2), dim3(512), 0, stream>>>(h2, W3t, b3, meta, out);
}

// Round 6
// 211.375 us; speedup vs baseline: 1.3012x; 1.3012x over previous
//
#include <hip/hip_runtime.h>
#include <hip/hip_bf16.h>
#include <cstdint>
#include <cstddef>

// Problem constants (fixed by the reference)
#define NCAT   8
#define DIN    64
#define HID    1024
#define NBATCH 256
#define HSEQ   64
#define NTOK   (NBATCH * HSEQ)   // 16384
#define MAXTILES 132             // 2-batch tiles: sum ceil(nb_c/2) <= 132
#define NWGG (8 * MAXTILES)      // 1056 blocks: 132 m-tiles x 8 n-panels

typedef __bf16 bf16x8 __attribute__((ext_vector_type(8)));
typedef __bf16 bf16x4 __attribute__((ext_vector_type(4)));
typedef float  f32x4  __attribute__((ext_vector_type(4)));

__device__ __forceinline__ void async16(const void* g, void* l) {
    __builtin_amdgcn_global_load_lds(
        (const __attribute__((address_space(1))) unsigned int*)g,
        (__attribute__((address_space(3))) unsigned int*)l,
        16, 0, 0);
}

// ---------------- setup: counting-sort batches by category, build tile table ----------------
// meta (ints): order[256]@0, tileB0[..]@256, tileB1[..]@416, tileCat[..]@576, ntiles@736
__global__ void setup_kernel(const int* __restrict__ cat, int* __restrict__ meta) {
    __shared__ int scat[NBATCH];
    __shared__ int cnt[NCAT], pfx[NCAT + 1];
    const int tid = threadIdx.x;
    const int c = cat[tid];
    scat[tid] = c;
    if (tid < NCAT) cnt[tid] = 0;
    __syncthreads();
    atomicAdd(&cnt[c], 1);
    __syncthreads();
    if (tid == 0) {
        pfx[0] = 0;
        for (int i = 0; i < NCAT; ++i) pfx[i + 1] = pfx[i] + cnt[i];
    }
    __syncthreads();
    int r = 0;
    for (int b = 0; b < tid; ++b) r += (scat[b] == c);
    meta[pfx[c] + r] = tid;                 // order[]
    __threadfence();
    __syncthreads();
    if (tid == 0) {
        int nt = 0;
        for (int cc = 0; cc < NCAT; ++cc) {
            const int base = pfx[cc], n = cnt[cc];
            for (int j = 0; j < n; j += 2) {
                meta[256 + nt] = meta[base + j];
                meta[416 + nt] = (j + 1 < n) ? meta[base + j + 1] : -1;
                meta[576 + nt] = cc;
                ++nt;
            }
        }
        meta[736] = nt;
    }
}

// ---------------- prep kernels ----------------

__global__ void pe_kernel(float* __restrict__ pe) {
    const int t = blockIdx.x;        // 0..63
    const int i = threadIdx.x;       // 0..511
    const float div = expf((float)(2 * i) * (-9.210340371976184f / 1024.f));
    const float a = (float)t * div;
    pe[t * HID + 2 * i]     = sinf(a);
    pe[t * HID + 2 * i + 1] = cosf(a);
}

__global__ void cvt_x_kernel(const float* __restrict__ x, __bf16* __restrict__ xb) {
    const size_t i = (size_t)blockIdx.x * blockDim.x + threadIdx.x;
    const float4 v = ((const float4*)x)[i];
    bf16x4 o = { (__bf16)v.x, (__bf16)v.y, (__bf16)v.z, (__bf16)v.w };
    *(bf16x4*)(xb + 4 * i) = o;
}

// W [C][K][N] f32 -> Wt [C][N][K] bf16 (64x64 LDS-tiled transpose)
template <int WHICH>
__global__ __launch_bounds__(256)
void transpose_kernel(const float* __restrict__ W, __bf16* __restrict__ Wt,
                      const int K, const int N) {
    __shared__ float tile[64][65];
    const int c = blockIdx.z;
    const float* Wc = W + (size_t)c * K * N;
    __bf16* Wtc = Wt + (size_t)c * N * K;
    const int k0 = blockIdx.y * 64, n0 = blockIdx.x * 64;
    const int t = threadIdx.x;
    const int cl = (t & 15) * 4, rw = t >> 4;
#pragma unroll
    for (int p = 0; p < 4; ++p) {
        const int r = rw + p * 16;
        const float4 v = *(const float4*)(Wc + (size_t)(k0 + r) * N + (n0 + cl));
        tile[r][cl]     = v.x;
        tile[r][cl + 1] = v.y;
        tile[r][cl + 2] = v.z;
        tile[r][cl + 3] = v.w;
    }
    __syncthreads();
    const int n = t >> 2, ks = (t & 3) * 16;
    bf16x8 o0, o1;
#pragma unroll
    for (int i = 0; i < 8; ++i) o0[i] = (__bf16)tile[ks + i][n];
#pragma unroll
    for (int i = 0; i < 8; ++i) o1[i] = (__bf16)tile[ks + 8 + i][n];
    __bf16* dst = Wtc + (size_t)(n0 + n) * K + (k0 + ks);
    *(bf16x8*)dst = o0;
    *(bf16x8*)(dst + 8) = o1;
}

// ---------------- category-grouped 128x128 GEMM, m97-replica ----------------
// A: [NTOK][K] bf16 row-major. Bt: [C][HID][K] bf16. 2 same-category batches
// per m-tile (128 rows). 4 waves (2m x 2n), each 64x64 (4x4 of 16x16x32 MFMA).
// Single-buffered 32 KB LDS, 2-barrier __syncthreads K-loop, gload_lds 16B.
// NO min-waves bound: regalloc free (m97: 164 VGPR, ~3 blocks/CU, 874-912 TF).
// XCD swizzle, m-chunk ownership: XCD x owns wgid [x*132, x*132+132) =
// ~17 contiguous category-sorted m-tiles x all 8 n-panels -> per-XCD B
// working set = 1-3 categories (2-6 MB, L2-resident), A chunk ~4 MB.
// T2 slot-XOR swizzle on global source + ds_read (LDS dest linear).
// EPI: 0 = +bias, relu, +pe -> bf16 ; 1 = +bias, relu -> bf16 ; 2 = +bias -> f32
template <int K, int EPI>
__device__ __forceinline__ void gemm_body(
        const __bf16* __restrict__ A, const __bf16* __restrict__ Bt,
        const float* __restrict__ bias, const float* __restrict__ pe,
        const int* __restrict__ meta,
        __bf16* __restrict__ hout, float* __restrict__ fout) {
    __shared__ __bf16 Ab[128 * 64];    // 16 KB
    __shared__ __bf16 Bb[128 * 64];    // 16 KB
    const int tid = threadIdx.x;       // 0..255
    const int lane = tid & 63;
    const int wv = tid >> 6;           // 0..3
    const int wm = wv >> 1, wn = wv & 1;
    // XCD swizzle: 1056 = 8 * 132; XCD x -> contiguous global (mt,np) range
    const int orig = blockIdx.x;
    const int wgid = (orig & 7) * MAXTILES + (orig >> 3);
    const int mt = wgid >> 3;
    const int n0 = (wgid & 7) * 128;
    if (mt >= meta[736]) return;       // block-uniform
    const int b0  = meta[256 + mt];
    const int b1  = meta[416 + mt];
    const int cid = meta[576 + mt];
    const int bb  = (b1 < 0) ? b0 : b1;

    const char* Ag0 = (const char*)(A + (size_t)b0 * HSEQ * K);
    const char* Ag1 = (const char*)(A + (size_t)bb * HSEQ * K);
    const char* Bg  = (const char*)(Bt + ((size_t)cid * HID + n0) * K);

    // staging: row = 128 B = 8 thr x 16 B; 256 thr -> 32 rows/issue; 4 issues each
    const int srow = tid >> 3;          // 0..31
    // T2: source slot pre-swizzle; LDS dest linear (slot s holds global slot s^(row&7))
    const int scol_sw = (((tid & 7) ^ (srow & 7)) * 16);

    f32x4 acc[4][4] = {};
    const int lr = lane & 15, lh = lane >> 4;
    const int rsw = lr & 7;

    const int NT = K / 64;
    for (int t = 0; t < NT; ++t) {
        const size_t kb = (size_t)t * 128;
#pragma unroll
        for (int j = 0; j < 4; ++j) {   // A tile rows j*32 + srow (b0 rows 0..63, b1 64..127)
            const int row = j * 32 + srow;
            const char* src = (j < 2 ? Ag0 + (size_t)row * (K * 2)
                                     : Ag1 + (size_t)(row - 64) * (K * 2)) + kb + scol_sw;
            async16(src, (char*)Ab + j * 4096 + tid * 16);
        }
#pragma unroll
        for (int j = 0; j < 4; ++j) {   // B tile rows j*32 + srow
            const int row = j * 32 + srow;
            async16(Bg + (size_t)row * (K * 2) + kb + scol_sw,
                    (char*)Bb + j * 4096 + tid * 16);
        }
        __syncthreads();               // vmcnt drain: tile staged
#pragma unroll
        for (int kk = 0; kk < 2; ++kk) {
            bf16x8 af[4], bfr[4];
            const int soff = ((((kk << 2) | lh) ^ rsw) << 4);
#pragma unroll
            for (int mi = 0; mi < 4; ++mi)
                af[mi] = *(const bf16x8*)((const char*)Ab + (wm * 64 + mi * 16 + lr) * 128 + soff);
#pragma unroll
            for (int ni = 0; ni < 4; ++ni)
                bfr[ni] = *(const bf16x8*)((const char*)Bb + (wn * 64 + ni * 16 + lr) * 128 + soff);
#pragma unroll
            for (int mi = 0; mi < 4; ++mi)
#pragma unroll
                for (int ni = 0; ni < 4; ++ni)
                    acc[mi][ni] = __builtin_amdgcn_mfma_f32_16x16x32_bf16(
                        af[mi], bfr[ni], acc[mi][ni], 0, 0, 0);
        }
        __syncthreads();               // all reads done before restage
    }

    // epilogue: C/D layout col = lane&15, row = (lane>>4)*4 + r
    const bool doStore = (wm == 0) || (b1 >= 0);
    if (!doStore) return;
    const int batch = wm ? b1 : b0;
#pragma unroll
    for (int ni = 0; ni < 4; ++ni) {
        const int n = n0 + wn * 64 + ni * 16 + lr;
        const float bv = bias[cid * HID + n];
#pragma unroll
        for (int mi = 0; mi < 4; ++mi) {
#pragma unroll
            for (int r = 0; r < 4; ++r) {
                const int tok = mi * 16 + lh * 4 + r;   // token within batch = PE index
                const size_t gi = ((size_t)batch * HSEQ + tok) * HID + n;
                float v = acc[mi][ni][r] + bv;
                if constexpr (EPI == 0) {
                    v = fmaxf(v, 0.f) + pe[tok * HID + n];
                    hout[gi] = (__bf16)v;
                } else if constexpr (EPI == 1) {
                    v = fmaxf(v, 0.f);
                    hout[gi] = (__bf16)v;
                } else {
                    fout[gi] = v;
                }
            }
        }
    }
}

// Distinct names per layer for rocprof attribution. No min-waves bound.
__global__ __launch_bounds__(256)
void gemm_l1(const __bf16* __restrict__ A, const __bf16* __restrict__ Bt,
             const float* __restrict__ bias, const float* __restrict__ pe,
             const int* __restrict__ meta, __bf16* __restrict__ hout) {
    gemm_body<DIN, 0>(A, Bt, bias, pe, meta, hout, nullptr);
}
__global__ __launch_bounds__(256)
void gemm_l2(const __bf16* __restrict__ A, const __bf16* __restrict__ Bt,
             const float* __restrict__ bias,
             const int* __restrict__ meta, __bf16* __restrict__ hout) {
    gemm_body<HID, 1>(A, Bt, bias, nullptr, meta, hout, nullptr);
}
__global__ __launch_bounds__(256)
void gemm_l3(const __bf16* __restrict__ A, const __bf16* __restrict__ Bt,
             const float* __restrict__ bias,
             const int* __restrict__ meta, float* __restrict__ fout) {
    gemm_body<HID, 2>(A, Bt, bias, nullptr, meta, nullptr, fout);
}

// ---------------- launcher ----------------

extern "C" void kernel_launch(void* const* d_in, const int* in_sizes, int n_in,
                              void* d_out, int out_size, void* d_ws, size_t ws_size,
                              hipStream_t stream) {
    (void)in_sizes; (void)n_in; (void)out_size; (void)ws_size;
    const float* x   = (const float*)d_in[0];
    const int*   cat = (const int*)d_in[1];
    const float* W1  = (const float*)d_in[2];
    const float* b1  = (const float*)d_in[3];
    const float* W2  = (const float*)d_in[4];
    const float* b2  = (const float*)d_in[5];
    const float* W3  = (const float*)d_in[6];
    const float* b3  = (const float*)d_in[7];
    float* out = (float*)d_out;

    // Workspace layout (67.1 MB; xb/W1t/pe are dead after L1 and time-alias h2):
    char* ws = (char*)d_ws;
    int*    meta = (int*)ws;                             // [0, 8192)
    __bf16* xb   = (__bf16*)(ws + 8192);                 // 2 MB   (L1 only)
    __bf16* W1t  = (__bf16*)(ws + 8192 + 2097152);       // 1 MB   (L1 only)
    float*  pe   = (float*) (ws + 8192 + 3145728);       // 256 KB (L1 only)
    __bf16* h2   = (__bf16*)(ws + 8192);                 // 32 MB  (aliases the above)
    __bf16* W2t  = (__bf16*)(ws + 33562624);             // 16 MB
    __bf16* W3t  = (__bf16*)(ws + 50339840);             // 16 MB
    // h1 (bf16, 32 MB) lives in the first half of d_out (f32 64 MB);
    // fully consumed by L2 before L3 overwrites d_out.
    __bf16* h1 = (__bf16*)d_out;

    setup_kernel<<<dim3(1), dim3(NBATCH), 0, stream>>>(cat, meta);
    pe_kernel<<<dim3(HSEQ), dim3(512), 0, stream>>>(pe);
    cvt_x_kernel<<<dim3(NTOK * DIN / 4 / 256), dim3(256), 0, stream>>>(x, xb);
    transpose_kernel<1><<<dim3(16, 1, NCAT),  dim3(256), 0, stream>>>(W1, W1t, DIN, HID);
    transpose_kernel<2><<<dim3(16, 16, NCAT), dim3(256), 0, stream>>>(W2, W2t, HID, HID);
    transpose_kernel<3><<<dim3(16, 16, NCAT), dim3(256), 0, stream>>>(W3, W3t, HID, HID);

    gemm_l1<<<dim3(NWGG), dim3(256), 0, stream>>>(xb, W1t, b1, pe, meta, h1);
    gemm_l2<<<dim3(NWGG), dim3(256), 0, stream>>>(h1, W2t, b2, meta, h2);
    gemm_l3<<<dim3(NWGG), dim3(256), 0, stream>>>(h2, W3t, b3, meta, out);
}

// Round 7
// 209.431 us; speedup vs baseline: 1.3133x; 1.0093x over previous
//
#include <hip/hip_runtime.h>
#include <hip/hip_bf16.h>
#include <cstdint>
#include <cstddef>

// Problem constants (fixed by the reference)
#define NCAT   8
#define DIN    64
#define HID    1024
#define NBATCH 256
#define HSEQ   64
#define NTOK   (NBATCH * HSEQ)   // 16384
#define MAXTILES 132             // 2-batch tiles: sum ceil(nb_c/2) <= 132
#define NWGG (8 * MAXTILES)      // 1056 blocks for L1 (128x128 tiles)
#define NWGP (4 * MAXTILES)      // 528 = 8*66 blocks for L2/L3 (128x256 tiles)

typedef __bf16 bf16x8 __attribute__((ext_vector_type(8)));
typedef __bf16 bf16x4 __attribute__((ext_vector_type(4)));
typedef float  f32x4  __attribute__((ext_vector_type(4)));

__device__ __forceinline__ void async16(const void* g, void* l) {
    __builtin_amdgcn_global_load_lds(
        (const __attribute__((address_space(1))) unsigned int*)g,
        (__attribute__((address_space(3))) unsigned int*)l,
        16, 0, 0);
}

// ---------------- setup: counting-sort batches by category, build tile table ----------------
// meta (ints): order[256]@0, tileB0[..]@256, tileB1[..]@416, tileCat[..]@576, ntiles@736
__global__ void setup_kernel(const int* __restrict__ cat, int* __restrict__ meta) {
    __shared__ int scat[NBATCH];
    __shared__ int cnt[NCAT], pfx[NCAT + 1];
    const int tid = threadIdx.x;
    const int c = cat[tid];
    scat[tid] = c;
    if (tid < NCAT) cnt[tid] = 0;
    __syncthreads();
    atomicAdd(&cnt[c], 1);
    __syncthreads();
    if (tid == 0) {
        pfx[0] = 0;
        for (int i = 0; i < NCAT; ++i) pfx[i + 1] = pfx[i] + cnt[i];
    }
    __syncthreads();
    int r = 0;
    for (int b = 0; b < tid; ++b) r += (scat[b] == c);
    meta[pfx[c] + r] = tid;                 // order[]
    __threadfence();
    __syncthreads();
    if (tid == 0) {
        int nt = 0;
        for (int cc = 0; cc < NCAT; ++cc) {
            const int base = pfx[cc], n = cnt[cc];
            for (int j = 0; j < n; j += 2) {
                meta[256 + nt] = meta[base + j];
                meta[416 + nt] = (j + 1 < n) ? meta[base + j + 1] : -1;
                meta[576 + nt] = cc;
                ++nt;
            }
        }
        meta[736] = nt;
    }
}

// ---------------- prep kernels ----------------

__global__ void pe_kernel(float* __restrict__ pe) {
    const int t = blockIdx.x;        // 0..63
    const int i = threadIdx.x;       // 0..511
    const float div = expf((float)(2 * i) * (-9.210340371976184f / 1024.f));
    const float a = (float)t * div;
    pe[t * HID + 2 * i]     = sinf(a);
    pe[t * HID + 2 * i + 1] = cosf(a);
}

__global__ void cvt_x_kernel(const float* __restrict__ x, __bf16* __restrict__ xb) {
    const size_t i = (size_t)blockIdx.x * blockDim.x + threadIdx.x;
    const float4 v = ((const float4*)x)[i];
    bf16x4 o = { (__bf16)v.x, (__bf16)v.y, (__bf16)v.z, (__bf16)v.w };
    *(bf16x4*)(xb + 4 * i) = o;
}

// W [C][K][N] f32 -> Wt [C][N][K] bf16 (64x64 LDS-tiled transpose)
template <int WHICH>
__global__ __launch_bounds__(256)
void transpose_kernel(const float* __restrict__ W, __bf16* __restrict__ Wt,
                      const int K, const int N) {
    __shared__ float tile[64][65];
    const int c = blockIdx.z;
    const float* Wc = W + (size_t)c * K * N;
    __bf16* Wtc = Wt + (size_t)c * N * K;
    const int k0 = blockIdx.y * 64, n0 = blockIdx.x * 64;
    const int t = threadIdx.x;
    const int cl = (t & 15) * 4, rw = t >> 4;
#pragma unroll
    for (int p = 0; p < 4; ++p) {
        const int r = rw + p * 16;
        const float4 v = *(const float4*)(Wc + (size_t)(k0 + r) * N + (n0 + cl));
        tile[r][cl]     = v.x;
        tile[r][cl + 1] = v.y;
        tile[r][cl + 2] = v.z;
        tile[r][cl + 3] = v.w;
    }
    __syncthreads();
    const int n = t >> 2, ks = (t & 3) * 16;
    bf16x8 o0, o1;
#pragma unroll
    for (int i = 0; i < 8; ++i) o0[i] = (__bf16)tile[ks + i][n];
#pragma unroll
    for (int i = 0; i < 8; ++i) o1[i] = (__bf16)tile[ks + 8 + i][n];
    __bf16* dst = Wtc + (size_t)(n0 + n) * K + (k0 + ks);
    *(bf16x8*)dst = o0;
    *(bf16x8*)(dst + 8) = o1;
}

// ---------------- L1: 128x128 2-batch GEMM (round-6 body, K=64, NT=1) ----------------
__global__ __launch_bounds__(256)
void gemm_l1(const __bf16* __restrict__ A, const __bf16* __restrict__ Bt,
             const float* __restrict__ bias, const float* __restrict__ pe,
             const int* __restrict__ meta, __bf16* __restrict__ hout) {
    constexpr int K = DIN;
    __shared__ __align__(16) __bf16 Ab[128 * 64];
    __shared__ __align__(16) __bf16 Bb[128 * 64];
    const int tid = threadIdx.x;
    const int lane = tid & 63;
    const int wv = tid >> 6;
    const int wm = wv >> 1, wn = wv & 1;
    const int orig = blockIdx.x;
    const int wgid = (orig & 7) * MAXTILES + (orig >> 3);
    const int mt = wgid >> 3;
    const int n0 = (wgid & 7) * 128;
    if (mt >= meta[736]) return;
    const int b0  = meta[256 + mt];
    const int b1  = meta[416 + mt];
    const int cid = meta[576 + mt];
    const int bb  = (b1 < 0) ? b0 : b1;

    const char* Ag0 = (const char*)(A + (size_t)b0 * HSEQ * K);
    const char* Ag1 = (const char*)(A + (size_t)bb * HSEQ * K);
    const char* Bg  = (const char*)(Bt + ((size_t)cid * HID + n0) * K);

    const int srow = tid >> 3;          // 0..31
    const int scol_sw = (((tid & 7) ^ (srow & 7)) * 16);

#pragma unroll
    for (int j = 0; j < 4; ++j) {
        const int row = j * 32 + srow;
        const char* src = (j < 2 ? Ag0 + (size_t)row * (K * 2)
                                 : Ag1 + (size_t)(row - 64) * (K * 2)) + scol_sw;
        async16(src, (char*)Ab + j * 4096 + tid * 16);
    }
#pragma unroll
    for (int j = 0; j < 4; ++j) {
        const int row = j * 32 + srow;
        async16(Bg + (size_t)row * (K * 2) + scol_sw, (char*)Bb + j * 4096 + tid * 16);
    }

    f32x4 acc[4][4] = {};
    const int lr = lane & 15, lh = lane >> 4;
    const int rsw = lr & 7;
    __syncthreads();
#pragma unroll
    for (int kk = 0; kk < 2; ++kk) {
        bf16x8 af[4], bfr[4];
        const int soff = ((((kk << 2) | lh) ^ rsw) << 4);
#pragma unroll
        for (int mi = 0; mi < 4; ++mi)
            af[mi] = *(const bf16x8*)((const char*)Ab + (wm * 64 + mi * 16 + lr) * 128 + soff);
#pragma unroll
        for (int ni = 0; ni < 4; ++ni)
            bfr[ni] = *(const bf16x8*)((const char*)Bb + (wn * 64 + ni * 16 + lr) * 128 + soff);
#pragma unroll
        for (int mi = 0; mi < 4; ++mi)
#pragma unroll
            for (int ni = 0; ni < 4; ++ni)
                acc[mi][ni] = __builtin_amdgcn_mfma_f32_16x16x32_bf16(
                    af[mi], bfr[ni], acc[mi][ni], 0, 0, 0);
    }

    const bool doStore = (wm == 0) || (b1 >= 0);
    if (!doStore) return;
    const int batch = wm ? b1 : b0;
#pragma unroll
    for (int ni = 0; ni < 4; ++ni) {
        const int n = n0 + wn * 64 + ni * 16 + lr;
        const float bv = bias[cid * HID + n];
#pragma unroll
        for (int mi = 0; mi < 4; ++mi) {
#pragma unroll
            for (int r = 0; r < 4; ++r) {
                const int tok = mi * 16 + lh * 4 + r;
                const size_t gi = ((size_t)batch * HSEQ + tok) * HID + n;
                float v = fmaxf(acc[mi][ni][r] + bv, 0.f) + pe[tok * HID + n];
                hout[gi] = (__bf16)v;
            }
        }
    }
}

// ---------------- L2/L3: 128x256 counted-vmcnt pipeline, 3-deep LDS ring ----------------
// K=1024 = 16 tiles of BK=64. LDS = 3 x (A 16K + B 32K) = 144 KB (1 block/CU).
// 8 waves (2M x 4N), per-wave 64x64, acc[4][4]. Per tile: 2 phases (kk=0,1),
// each {8 ds_read -> s_barrier -> lgkmcnt(0) -> setprio 16 MFMA -> s_barrier}.
// Stage tile j+2 (burst, 6 gloads) at tile j kk0; boundary wait = vmcnt(6)
// (youngest 6 = tile j+2's) -- never 0 mid-loop (T4). Ledger:
//   RAW: tile j's 6 gloads issued at j-2 kk0; end-of-(j-1) vmcnt(6) retires them.
//   WAR: buf (bcur+2)%3 last read at tile j-1 kk1 (drained by lgkmcnt(0) before
//        that phase's barrier); gloads issued after the boundary barrier.
// T2 slot-XOR swizzle on source + ds_read. T1 XCD swizzle (528 = 8*66).
// EPI: 1 = +bias, relu -> bf16 ; 2 = +bias -> f32
template <int EPI>
__device__ __forceinline__ void gemm_pipe(
        const __bf16* __restrict__ A, const __bf16* __restrict__ Bt,
        const float* __restrict__ bias, const int* __restrict__ meta,
        __bf16* __restrict__ hout, float* __restrict__ fout) {
    constexpr int K = HID;
    constexpr int NT = K / 64;           // 16
    __shared__ __align__(16) __bf16 Ab[3][128 * 64];   // 3 x 16 KB
    __shared__ __align__(16) __bf16 Bb[3][256 * 64];   // 3 x 32 KB
    const int tid = threadIdx.x;         // 0..511
    const int lane = tid & 63;
    const int wv = tid >> 6;             // 0..7
    const int wm = wv >> 2, wn = wv & 3; // 2M x 4N
    const int orig = blockIdx.x;
    const int wgid = (orig & 7) * 66 + (orig >> 3);   // bijective, 528 = 8*66
    const int mt = wgid >> 2;
    const int n0 = (wgid & 3) * 256;
    if (mt >= meta[736]) return;         // block-uniform
    const int b0  = meta[256 + mt];
    const int b1  = meta[416 + mt];
    const int cid = meta[576 + mt];
    const int bb  = (b1 < 0) ? b0 : b1;

    const char* Ag0 = (const char*)(A + (size_t)b0 * HSEQ * K);
    const char* Ag1 = (const char*)(A + (size_t)bb * HSEQ * K);
    const char* Bg  = (const char*)(Bt + ((size_t)cid * HID + n0) * K);

    const int srow = tid >> 3;           // 0..63
    const int scol_sw = (((tid & 7) ^ (srow & 7)) * 16);

    auto stage = [&](int buf, int kt) {
        const size_t kb = (size_t)kt * 128;
        char* Ad = (char*)&Ab[0][0] + buf * 16384;
        char* Bd = (char*)&Bb[0][0] + buf * 32768;
        async16(Ag0 + (size_t)srow * (2 * K) + kb + scol_sw, Ad + tid * 16);
        async16(Ag1 + (size_t)srow * (2 * K) + kb + scol_sw, Ad + 8192 + tid * 16);
#pragma unroll
        for (int q = 0; q < 4; ++q)
            async16(Bg + (size_t)(q * 64 + srow) * (2 * K) + kb + scol_sw,
                    Bd + q * 8192 + tid * 16);
    };

    f32x4 acc[4][4] = {};
    const int lr = lane & 15, lh = lane >> 4;
    const int rsw = lr & 7;

    // prologue: tiles 0,1 in flight; retire tile 0 (vmcnt(6): tile1's 6 remain)
    stage(0, 0);
    stage(1, 1);
    asm volatile("s_waitcnt vmcnt(6)" ::: "memory");
    __builtin_amdgcn_sched_barrier(0);
    asm volatile("s_barrier" ::: "memory");
    __builtin_amdgcn_sched_barrier(0);

    int bcur = 0;
    for (int j = 0; j < NT; ++j) {
        const char* Abase = (const char*)&Ab[0][0] + bcur * 16384;
        const char* Bbase = (const char*)&Bb[0][0] + bcur * 32768;
        const bool more2 = (j + 2 < NT);
#pragma unroll
        for (int kk = 0; kk < 2; ++kk) {
            bf16x8 af[4], bfr[4];
            const int soff = ((((kk << 2) | lh) ^ rsw) << 4);
#pragma unroll
            for (int mi = 0; mi < 4; ++mi)
                af[mi] = *(const bf16x8*)(Abase + (wm * 64 + mi * 16 + lr) * 128 + soff);
#pragma unroll
            for (int ni = 0; ni < 4; ++ni)
                bfr[ni] = *(const bf16x8*)(Bbase + (wn * 64 + ni * 16 + lr) * 128 + soff);
            if (kk == 0 && more2)
                stage((bcur + 2 >= 3) ? bcur - 1 : bcur + 2, j + 2);
            __builtin_amdgcn_sched_barrier(0);
            asm volatile("s_barrier" ::: "memory");
            asm volatile("s_waitcnt lgkmcnt(0)" ::: "memory");
            __builtin_amdgcn_sched_barrier(0);
            __builtin_amdgcn_s_setprio(1);
#pragma unroll
            for (int mi = 0; mi < 4; ++mi)
#pragma unroll
                for (int ni = 0; ni < 4; ++ni)
                    acc[mi][ni] = __builtin_amdgcn_mfma_f32_16x16x32_bf16(
                        af[mi], bfr[ni], acc[mi][ni], 0, 0, 0);
            __builtin_amdgcn_s_setprio(0);
            __builtin_amdgcn_sched_barrier(0);
            if (kk == 1) {             // boundary: retire tile j+1 (T4 counted)
                if (more2) asm volatile("s_waitcnt vmcnt(6)" ::: "memory");
                else       asm volatile("s_waitcnt vmcnt(0)" ::: "memory");
            }
            asm volatile("s_barrier" ::: "memory");
            __builtin_amdgcn_sched_barrier(0);
        }
        bcur = (bcur + 1 >= 3) ? 0 : bcur + 1;
    }

    // epilogue: C/D layout col = lane&15, row = (lane>>4)*4 + r
    const bool doStore = (wm == 0) || (b1 >= 0);
    if (!doStore) return;
    const int batch = wm ? b1 : b0;
#pragma unroll
    for (int ni = 0; ni < 4; ++ni) {
        const int n = n0 + wn * 64 + ni * 16 + lr;
        const float bv = bias[cid * HID + n];
#pragma unroll
        for (int mi = 0; mi < 4; ++mi) {
#pragma unroll
            for (int r = 0; r < 4; ++r) {
                const int tok = mi * 16 + lh * 4 + r;
                const size_t gi = ((size_t)batch * HSEQ + tok) * HID + n;
                float v = acc[mi][ni][r] + bv;
                if constexpr (EPI == 1) {
                    hout[gi] = (__bf16)fmaxf(v, 0.f);
                } else {
                    fout[gi] = v;
                }
            }
        }
    }
}

__global__ __launch_bounds__(512)
void gemm_l2(const __bf16* __restrict__ A, const __bf16* __restrict__ Bt,
             const float* __restrict__ bias,
             const int* __restrict__ meta, __bf16* __restrict__ hout) {
    gemm_pipe<1>(A, Bt, bias, meta, hout, nullptr);
}
__global__ __launch_bounds__(512)
void gemm_l3(const __bf16* __restrict__ A, const __bf16* __restrict__ Bt,
             const float* __restrict__ bias,
             const int* __restrict__ meta, float* __restrict__ fout) {
    gemm_pipe<2>(A, Bt, bias, meta, nullptr, fout);
}

// ---------------- launcher ----------------

extern "C" void kernel_launch(void* const* d_in, const int* in_sizes, int n_in,
                              void* d_out, int out_size, void* d_ws, size_t ws_size,
                              hipStream_t stream) {
    (void)in_sizes; (void)n_in; (void)out_size; (void)ws_size;
    const float* x   = (const float*)d_in[0];
    const int*   cat = (const int*)d_in[1];
    const float* W1  = (const float*)d_in[2];
    const float* b1  = (const float*)d_in[3];
    const float* W2  = (const float*)d_in[4];
    const float* b2  = (const float*)d_in[5];
    const float* W3  = (const float*)d_in[6];
    const float* b3  = (const float*)d_in[7];
    float* out = (float*)d_out;

    // Workspace layout (67.1 MB; xb/W1t/pe are dead after L1 and time-alias h2):
    char* ws = (char*)d_ws;
    int*    meta = (int*)ws;                             // [0, 8192)
    __bf16* xb   = (__bf16*)(ws + 8192);                 // 2 MB   (L1 only)
    __bf16* W1t  = (__bf16*)(ws + 8192 + 2097152);       // 1 MB   (L1 only)
    float*  pe   = (float*) (ws + 8192 + 3145728);       // 256 KB (L1 only)
    __bf16* h2   = (__bf16*)(ws + 8192);                 // 32 MB  (aliases the above)
    __bf16* W2t  = (__bf16*)(ws + 33562624);             // 16 MB
    __bf16* W3t  = (__bf16*)(ws + 50339840);             // 16 MB
    // h1 (bf16, 32 MB) lives in the first half of d_out (f32 64 MB);
    // fully consumed by L2 before L3 overwrites d_out.
    __bf16* h1 = (__bf16*)d_out;

    setup_kernel<<<dim3(1), dim3(NBATCH), 0, stream>>>(cat, meta);
    pe_kernel<<<dim3(HSEQ), dim3(512), 0, stream>>>(pe);
    cvt_x_kernel<<<dim3(NTOK * DIN / 4 / 256), dim3(256), 0, stream>>>(x, xb);
    transpose_kernel<1><<<dim3(16, 1, NCAT),  dim3(256), 0, stream>>>(W1, W1t, DIN, HID);
    transpose_kernel<2><<<dim3(16, 16, NCAT), dim3(256), 0, stream>>>(W2, W2t, HID, HID);
    transpose_kernel<3><<<dim3(16, 16, NCAT), dim3(256), 0, stream>>>(W3, W3t, HID, HID);

    gemm_l1<<<dim3(NWGG), dim3(256), 0, stream>>>(xb, W1t, b1, pe, meta, h1);
    gemm_l2<<<dim3(NWGP), dim3(512), 0, stream>>>(h1, W2t, b2, meta, h2);
    gemm_l3<<<dim3(NWGP), dim3(512), 0, stream>>>(h2, W3t, b3, meta, out);
}